// Round 1
// baseline (118.264 us; speedup 1.0000x reference)
//
#include <hip/hip_runtime.h>
#include <math.h>

#define BLK 100          // BLOCK
#define NF  128          // N_freqs
#define NTOT (NF * BLK)  // 12800
#define P   104          // LDS pitch (floats): rows 16B-aligned, bank aliasing <= 2-way

// One workgroup per frequency block: build M = s*D + (1-s)*I in LDS,
// in-place non-pivoted LU, logdet = sum log|U_kk|, NaN if det <= 0.
__global__ __launch_bounds__(256) void lu_logdet_kernel(const float* __restrict__ w,
                                                        const float* __restrict__ L,
                                                        float* __restrict__ out) {
    __shared__ float a[BLK * P];
    __shared__ float red[256];
    __shared__ int   neg[256];

    const int f   = blockIdx.x;
    const int tid = threadIdx.x;

    // ---- load diag block f, fused transform: M[r][c] = s_r * D[r][c] + (r==c ? 1-s_r : 0)
    const float* base = L + (size_t)f * BLK * NTOT + (size_t)f * BLK;
    for (int q = tid; q < BLK * 25; q += 256) {        // 25 float4 per row
        const int r  = q / 25;
        const int c0 = (q - r * 25) * 4;
        const float4 v = *reinterpret_cast<const float4*>(base + (size_t)r * NTOT + c0);
        const float sv = 1.0f / (1.0f + expf(-w[f * BLK + r]));
        const float ds = 1.0f - sv;
        float4 m;
        m.x = sv * v.x + ((c0 + 0) == r ? ds : 0.0f);
        m.y = sv * v.y + ((c0 + 1) == r ? ds : 0.0f);
        m.z = sv * v.z + ((c0 + 2) == r ? ds : 0.0f);
        m.w = sv * v.w + ((c0 + 3) == r ? ds : 0.0f);
        *reinterpret_cast<float4*>(&a[r * P + c0]) = m;
    }
    __syncthreads();

    // ---- right-looking GE, no pivoting; 16x16 thread tile; 1 barrier per step
    const int cx = tid & 15;
    const int ry = tid >> 4;
    for (int k = 0; k < BLK - 1; ++k) {
        const float rinv = 1.0f / a[k * P + k];        // broadcast read
        for (int i = k + 1 + ry; i < BLK; i += 16) {
            const float fac = a[i * P + k] * rinv;
            for (int j = k + 1 + cx; j < BLK; j += 16)
                a[i * P + j] -= fac * a[k * P + j];
        }
        __syncthreads();
    }

    // ---- logdet from U diagonal
    float lsum = 0.0f;
    int   lneg = 0;
    if (tid < BLK) {
        const float d = a[tid * P + tid];
        lsum = logf(fabsf(d));                          // d==0 -> -inf -> caught below
        lneg = (d < 0.0f) ? 1 : 0;
    }
    red[tid] = lsum;
    neg[tid] = lneg;
    __syncthreads();
    for (int s = 128; s > 0; s >>= 1) {
        if (tid < s) { red[tid] += red[tid + s]; neg[tid] += neg[tid + s]; }
        __syncthreads();
    }
    if (tid == 0) {
        float ld = red[0];
        if ((neg[0] & 1) || !isfinite(ld)) ld = __int_as_float(0x7fc00000);  // NaN
        out[1 + f] = ld;
    }
}

// Sum the 128 logdets into out[0] (NaN propagates, matching jnp.sum of where(...))
__global__ __launch_bounds__(128) void sum_kernel(float* __restrict__ out) {
    const int t = threadIdx.x;
    float v = out[1 + t];
    v += __shfl_down(v, 32);
    v += __shfl_down(v, 16);
    v += __shfl_down(v, 8);
    v += __shfl_down(v, 4);
    v += __shfl_down(v, 2);
    v += __shfl_down(v, 1);
    __shared__ float ws2[2];
    if ((t & 63) == 0) ws2[t >> 6] = v;
    __syncthreads();
    if (t == 0) out[0] = ws2[0] + ws2[1];
}

extern "C" void kernel_launch(void* const* d_in, const int* in_sizes, int n_in,
                              void* d_out, int out_size, void* d_ws, size_t ws_size,
                              hipStream_t stream) {
    const float* w = (const float*)d_in[0];   // weights (12800,) f32
    const float* L = (const float*)d_in[1];   // L_kernel (12800,12800) f32
    float* out = (float*)d_out;               // [0]=sum, [1..128]=logdets
    lu_logdet_kernel<<<NF, 256, 0, stream>>>(w, L, out);
    sum_kernel<<<1, 128, 0, stream>>>(out);
}

// Round 2
// 61.628 us; speedup vs baseline: 1.9190x; 1.9190x over previous
//
#include <hip/hip_runtime.h>
#include <math.h>

#define BLK 100          // BLOCK
#define NF  128          // N_freqs
#define NTOT (NF * BLK)  // 12800
#define P   104          // LDS pitch (floats): rows 16B-aligned (416B), <=2-way bank aliasing

// One workgroup per frequency block: build M = s*D + (1-s)*I in LDS,
// in-place non-pivoted LU (full-row rank-1 updates; cols < k are dead),
// logdet = sum log|U_kk|, NaN if det <= 0.
//
// Thread mapping for the update: 4 waves; within a wave, lanes 0..24 handle
// float4 column-group g=lane of row i, lanes 32..56 handle row i+1. Rows
// k+1.. are distributed round-robin mod 8 over (wave, half). One
// ds_read_b128 per wave serves two rows; pivot row cached in regs per step.
__global__ __launch_bounds__(256) void lu_logdet_kernel(const float* __restrict__ w,
                                                        const float* __restrict__ L,
                                                        float* __restrict__ out) {
    __shared__ float a[BLK * P];
    __shared__ float red[256];
    __shared__ int   neg[256];

    const int f    = blockIdx.x;
    const int tid  = threadIdx.x;
    const int wave = tid >> 6;
    const int lane = tid & 63;
    const int half = lane >> 5;      // 0: row i, 1: row i+1
    const int g    = lane & 31;      // float4 column group, active if g < 25

    // ---- load diag block f, fused transform: M[r][c] = s_r * D[r][c] + (r==c ? 1-s_r : 0)
    const float* base = L + (size_t)f * BLK * NTOT + (size_t)f * BLK;
    for (int q = tid; q < BLK * 25; q += 256) {        // 25 float4 per row
        const int r  = q / 25;
        const int c0 = (q - r * 25) * 4;
        const float4 v = *reinterpret_cast<const float4*>(base + (size_t)r * NTOT + c0);
        const float sv = 1.0f / (1.0f + expf(-w[f * BLK + r]));
        const float ds = 1.0f - sv;
        float4 m;
        m.x = sv * v.x + ((c0 + 0) == r ? ds : 0.0f);
        m.y = sv * v.y + ((c0 + 1) == r ? ds : 0.0f);
        m.z = sv * v.z + ((c0 + 2) == r ? ds : 0.0f);
        m.w = sv * v.w + ((c0 + 3) == r ? ds : 0.0f);
        *reinterpret_cast<float4*>(&a[r * P + c0]) = m;
    }
    __syncthreads();

    // ---- right-looking GE, no pivoting; full-row float4 rank-1 updates
    for (int k = 0; k < BLK - 1; ++k) {
        const float rinv = 1.0f / a[k * P + k];        // broadcast read
        if (g < 25) {
            const int c4 = 4 * g;
            const float4 p4 = *reinterpret_cast<const float4*>(&a[k * P + c4]);
            int i = k + 1 + 2 * wave + half;
            // 2x unrolled: 4 LDS loads in flight before use
            for (; i + 8 < BLK; i += 16) {
                const int i2 = i + 8;
                float  fac1 = a[i  * P + k];
                float  fac2 = a[i2 * P + k];
                float4 v1 = *reinterpret_cast<const float4*>(&a[i  * P + c4]);
                float4 v2 = *reinterpret_cast<const float4*>(&a[i2 * P + c4]);
                fac1 *= rinv;
                fac2 *= rinv;
                v1.x -= fac1 * p4.x; v1.y -= fac1 * p4.y;
                v1.z -= fac1 * p4.z; v1.w -= fac1 * p4.w;
                v2.x -= fac2 * p4.x; v2.y -= fac2 * p4.y;
                v2.z -= fac2 * p4.z; v2.w -= fac2 * p4.w;
                *reinterpret_cast<float4*>(&a[i  * P + c4]) = v1;
                *reinterpret_cast<float4*>(&a[i2 * P + c4]) = v2;
            }
            for (; i < BLK; i += 8) {
                float  fac = a[i * P + k] * rinv;
                float4 v = *reinterpret_cast<const float4*>(&a[i * P + c4]);
                v.x -= fac * p4.x; v.y -= fac * p4.y;
                v.z -= fac * p4.z; v.w -= fac * p4.w;
                *reinterpret_cast<float4*>(&a[i * P + c4]) = v;
            }
        }
        __syncthreads();
    }

    // ---- logdet from U diagonal
    float lsum = 0.0f;
    int   lneg = 0;
    if (tid < BLK) {
        const float d = a[tid * P + tid];
        lsum = logf(fabsf(d));                          // d==0 -> -inf -> caught below
        lneg = (d < 0.0f) ? 1 : 0;
    }
    red[tid] = lsum;
    neg[tid] = lneg;
    __syncthreads();
    for (int s = 128; s > 0; s >>= 1) {
        if (tid < s) { red[tid] += red[tid + s]; neg[tid] += neg[tid + s]; }
        __syncthreads();
    }
    if (tid == 0) {
        float ld = red[0];
        if ((neg[0] & 1) || !isfinite(ld)) ld = __int_as_float(0x7fc00000);  // NaN
        out[1 + f] = ld;
    }
}

// Sum the 128 logdets into out[0] (NaN propagates, matching jnp.sum of where(...))
__global__ __launch_bounds__(128) void sum_kernel(float* __restrict__ out) {
    const int t = threadIdx.x;
    float v = out[1 + t];
    v += __shfl_down(v, 32);
    v += __shfl_down(v, 16);
    v += __shfl_down(v, 8);
    v += __shfl_down(v, 4);
    v += __shfl_down(v, 2);
    v += __shfl_down(v, 1);
    __shared__ float ws2[2];
    if ((t & 63) == 0) ws2[t >> 6] = v;
    __syncthreads();
    if (t == 0) out[0] = ws2[0] + ws2[1];
}

extern "C" void kernel_launch(void* const* d_in, const int* in_sizes, int n_in,
                              void* d_out, int out_size, void* d_ws, size_t ws_size,
                              hipStream_t stream) {
    const float* w = (const float*)d_in[0];   // weights (12800,) f32
    const float* L = (const float*)d_in[1];   // L_kernel (12800,12800) f32
    float* out = (float*)d_out;               // [0]=sum, [1..128]=logdets
    lu_logdet_kernel<<<NF, 256, 0, stream>>>(w, L, out);
    sum_kernel<<<1, 128, 0, stream>>>(out);
}